// Round 1
// baseline (615.059 us; speedup 1.0000x reference)
//
#include <hip/hip_runtime.h>
#include <cstdint>
#include <cstddef>

#define SEQ 2048
#define DMODEL 1024
#define NHEADS 16
#define HDIM 64

typedef __attribute__((ext_vector_type(8))) short short8;
typedef __attribute__((ext_vector_type(4))) float floatx4;

__device__ __forceinline__ short f2bf(float f) {
  union { float f; uint32_t u; } x; x.f = f;
  uint32_t r = (x.u + 0x7FFFu + ((x.u >> 16) & 1u)) >> 16;
  return (short)(uint16_t)r;
}

// ---------------- cast fp32 -> bf16 ----------------
__global__ __launch_bounds__(256) void cast_bf16_kernel(const float* __restrict__ src,
                                                        short* __restrict__ dst, int n) {
  int i = blockIdx.x * 256 + threadIdx.x;
  if (i < n) dst[i] = f2bf(src[i]);
}

// ---------------- transpose 1024x1024 fp32 -> bf16 (W[d][n] -> Wt[n][d]) ----------------
__global__ __launch_bounds__(256) void transpose_cast_kernel(const float* __restrict__ src,
                                                             short* __restrict__ dst) {
  __shared__ float tile[32][33];
  int tx = threadIdx.x, ty = threadIdx.y;
  int x = blockIdx.x * 32 + tx;
  int y0 = blockIdx.y * 32;
#pragma unroll
  for (int j = 0; j < 32; j += 8)
    tile[ty + j][tx] = src[(size_t)(y0 + ty + j) * DMODEL + x];
  __syncthreads();
  int xo = blockIdx.y * 32 + tx;
  int yo0 = blockIdx.x * 32;
#pragma unroll
  for (int j = 0; j < 32; j += 8)
    dst[(size_t)(yo0 + ty + j) * DMODEL + xo] = f2bf(tile[tx][ty + j]);
}

// ---------------- QKV GEMM: X[2048,1024] @ W -> q,k (head-major), vT (transposed) ----------------
// Wt: [3*1024 n][1024 d] bf16 (B^T layout). Wave computes 16(M) x 64(N).
__global__ __launch_bounds__(256) void qkv_gemm_kernel(const short* __restrict__ Xb,
                                                       const short* __restrict__ Wt,
                                                       short* __restrict__ q,
                                                       short* __restrict__ k,
                                                       short* __restrict__ vT) {
  int wave = threadIdx.x >> 6;
  int lane = threadIdx.x & 63;
  int lr = lane & 15;
  int quad = lane >> 4;
  int m0 = blockIdx.y * 64 + wave * 16;
  int n0 = blockIdx.x * 64;

  const short* Arow = Xb + (size_t)(m0 + lr) * DMODEL + quad * 8;
  const short* Brow = Wt + (size_t)(n0 + lr) * DMODEL + quad * 8;

  floatx4 acc[4] = {};
  for (int kb = 0; kb < DMODEL; kb += 32) {
    short8 a = *(const short8*)(Arow + kb);
#pragma unroll
    for (int f = 0; f < 4; ++f) {
      short8 b = *(const short8*)(Brow + (size_t)f * 16 * DMODEL + kb);
      acc[f] = __builtin_amdgcn_mfma_f32_16x16x32_bf16(a, b, acc[f], 0, 0, 0);
    }
  }

#pragma unroll
  for (int f = 0; f < 4; ++f) {
    int n = n0 + f * 16 + lr;
    int which = n >> 10;  // 0=q, 1=k, 2=v
    int nn = n & 1023;
    int h = nn >> 6, d = nn & 63;
#pragma unroll
    for (int r = 0; r < 4; ++r) {
      int row = m0 + quad * 4 + r;
      short hv = f2bf(acc[f][r]);
      if (which == 0)
        q[((size_t)h * SEQ + row) * HDIM + d] = hv;
      else if (which == 1)
        k[((size_t)h * SEQ + row) * HDIM + d] = hv;
      else
        vT[((size_t)h * HDIM + d) * SEQ + row] = hv;
    }
  }
}

// ---------------- Scores: S[h][m][n] = (Q K^T)/8, fp32 into probs region ----------------
__global__ __launch_bounds__(256) void scores_kernel(const short* __restrict__ q,
                                                     const short* __restrict__ k,
                                                     float* __restrict__ probs) {
  int h = blockIdx.z;
  int wave = threadIdx.x >> 6;
  int lane = threadIdx.x & 63;
  int lr = lane & 15;
  int quad = lane >> 4;
  int m0 = blockIdx.y * 16;
  int n0 = blockIdx.x * 256 + wave * 64;

  const short* Q = q + ((size_t)h * SEQ + m0 + lr) * HDIM + quad * 8;
  const short* K = k + (size_t)h * SEQ * HDIM;

  floatx4 acc[4] = {};
#pragma unroll
  for (int kb = 0; kb < HDIM; kb += 32) {
    short8 a = *(const short8*)(Q + kb);
#pragma unroll
    for (int f = 0; f < 4; ++f) {
      short8 b = *(const short8*)(K + (size_t)(n0 + f * 16 + lr) * HDIM + kb + quad * 8);
      acc[f] = __builtin_amdgcn_mfma_f32_16x16x32_bf16(a, b, acc[f], 0, 0, 0);
    }
  }

  float* Srow = probs + ((size_t)h * SEQ + m0) * SEQ;
#pragma unroll
  for (int f = 0; f < 4; ++f) {
#pragma unroll
    for (int r = 0; r < 4; ++r) {
      Srow[(size_t)(quad * 4 + r) * SEQ + n0 + f * 16 + lr] = acc[f][r] * 0.125f;
    }
  }
}

// ---------------- Row softmax in-place over 2048-length rows ----------------
__global__ __launch_bounds__(256) void softmax_kernel(float* __restrict__ probs) {
  float* p = probs + (size_t)blockIdx.x * SEQ;
  int t = threadIdx.x;
  int wave = t >> 6, lane = t & 63;

  floatx4 x0 = *(floatx4*)(p + t * 8);
  floatx4 x1 = *(floatx4*)(p + t * 8 + 4);

  float m = -3.4e38f;
#pragma unroll
  for (int j = 0; j < 4; ++j) m = fmaxf(m, fmaxf(x0[j], x1[j]));
#pragma unroll
  for (int o = 32; o >= 1; o >>= 1) m = fmaxf(m, __shfl_xor(m, o));
  __shared__ float rmax[4];
  __shared__ float rsum[4];
  if (lane == 0) rmax[wave] = m;
  __syncthreads();
  m = fmaxf(fmaxf(rmax[0], rmax[1]), fmaxf(rmax[2], rmax[3]));

  float s = 0.f;
#pragma unroll
  for (int j = 0; j < 4; ++j) {
    x0[j] = __expf(x0[j] - m);
    s += x0[j];
    x1[j] = __expf(x1[j] - m);
    s += x1[j];
  }
#pragma unroll
  for (int o = 32; o >= 1; o >>= 1) s += __shfl_xor(s, o);
  if (lane == 0) rsum[wave] = s;
  __syncthreads();
  s = rsum[0] + rsum[1] + rsum[2] + rsum[3];
  float inv = 1.0f / s;

#pragma unroll
  for (int j = 0; j < 4; ++j) { x0[j] *= inv; x1[j] *= inv; }
  *(floatx4*)(p + t * 8) = x0;
  *(floatx4*)(p + t * 8 + 4) = x1;
}

// ---------------- PV: context[m][h*64+d] = sum_n P[h][m][n] * V[h][n][d] ----------------
__global__ __launch_bounds__(256) void pv_kernel(const float* __restrict__ probs,
                                                 const short* __restrict__ vT,
                                                 float* __restrict__ ctx) {
  int h = blockIdx.y;
  int wave = threadIdx.x >> 6;
  int lane = threadIdx.x & 63;
  int lr = lane & 15;
  int quad = lane >> 4;
  int m0 = blockIdx.x * 64 + wave * 16;

  const float* P = probs + ((size_t)h * SEQ + m0 + lr) * SEQ + quad * 8;
  const short* V = vT + ((size_t)h * HDIM + lr) * SEQ + quad * 8;

  floatx4 acc[4] = {};
  for (int kb = 0; kb < SEQ; kb += 32) {
    floatx4 a0 = *(const floatx4*)(P + kb);
    floatx4 a1 = *(const floatx4*)(P + kb + 4);
    short8 a;
    a[0] = f2bf(a0[0]); a[1] = f2bf(a0[1]); a[2] = f2bf(a0[2]); a[3] = f2bf(a0[3]);
    a[4] = f2bf(a1[0]); a[5] = f2bf(a1[1]); a[6] = f2bf(a1[2]); a[7] = f2bf(a1[3]);
#pragma unroll
    for (int f = 0; f < 4; ++f) {
      short8 b = *(const short8*)(V + (size_t)f * 16 * SEQ + kb);
      acc[f] = __builtin_amdgcn_mfma_f32_16x16x32_bf16(a, b, acc[f], 0, 0, 0);
    }
  }

#pragma unroll
  for (int f = 0; f < 4; ++f) {
#pragma unroll
    for (int r = 0; r < 4; ++r) {
      int row = m0 + quad * 4 + r;
      int d = f * 16 + lr;
      ctx[(size_t)row * DMODEL + h * HDIM + d] = acc[f][r];
    }
  }
}

extern "C" void kernel_launch(void* const* d_in, const int* in_sizes, int n_in,
                              void* d_out, int out_size, void* d_ws, size_t ws_size,
                              hipStream_t stream) {
  const float* X = (const float*)d_in[0];
  const float* Wq = (const float*)d_in[1];
  const float* Wk = (const float*)d_in[2];
  const float* Wv = (const float*)d_in[3];

  float* ctx = (float*)d_out;
  float* probs = (float*)d_out + (size_t)SEQ * DMODEL;

  short* Xb = (short*)d_ws;                       // [2048][1024] bf16
  short* Wt = Xb + (size_t)SEQ * DMODEL;          // [3*1024][1024] bf16 (B^T)
  short* qb = Wt + (size_t)3 * DMODEL * DMODEL;   // [16][2048][64]
  short* kb = qb + (size_t)NHEADS * SEQ * HDIM;   // [16][2048][64]
  short* vT = kb + (size_t)NHEADS * SEQ * HDIM;   // [16][64][2048]

  cast_bf16_kernel<<<(SEQ * DMODEL + 255) / 256, 256, 0, stream>>>(X, Xb, SEQ * DMODEL);
  dim3 tb(32, 8), tg(32, 32);
  transpose_cast_kernel<<<tg, tb, 0, stream>>>(Wq, Wt);
  transpose_cast_kernel<<<tg, tb, 0, stream>>>(Wk, Wt + (size_t)DMODEL * DMODEL);
  transpose_cast_kernel<<<tg, tb, 0, stream>>>(Wv, Wt + (size_t)2 * DMODEL * DMODEL);

  qkv_gemm_kernel<<<dim3(48, 32), 256, 0, stream>>>(Xb, Wt, qb, kb, vT);
  scores_kernel<<<dim3(8, 128, 16), 256, 0, stream>>>(qb, kb, probs);
  softmax_kernel<<<NHEADS * SEQ, 256, 0, stream>>>(probs);
  pv_kernel<<<dim3(32, 16), 256, 0, stream>>>(probs, vT, ctx);
}

// Round 2
// 542.287 us; speedup vs baseline: 1.1342x; 1.1342x over previous
//
#include <hip/hip_runtime.h>
#include <cstdint>
#include <cstddef>

#define SEQ 2048
#define DMODEL 1024
#define NHEADS 16
#define HDIM 64

typedef __attribute__((ext_vector_type(8))) short short8;
typedef __attribute__((ext_vector_type(4))) float floatx4;

__device__ __forceinline__ short f2bf(float f) {
  union { float f; uint32_t u; } x; x.f = f;
  uint32_t r = (x.u + 0x7FFFu + ((x.u >> 16) & 1u)) >> 16;
  return (short)(uint16_t)r;
}

// ---------------- cast fp32 -> bf16 ----------------
__global__ __launch_bounds__(256) void cast_bf16_kernel(const float* __restrict__ src,
                                                        short* __restrict__ dst, int n) {
  int i = blockIdx.x * 256 + threadIdx.x;
  if (i < n) dst[i] = f2bf(src[i]);
}

// ---------------- transpose 1024x1024 fp32 -> bf16 (W[d][n] -> Wt[n][d]) ----------------
__global__ __launch_bounds__(256) void transpose_cast_kernel(const float* __restrict__ src,
                                                             short* __restrict__ dst) {
  __shared__ float tile[32][33];
  int tx = threadIdx.x, ty = threadIdx.y;
  int x = blockIdx.x * 32 + tx;
  int y0 = blockIdx.y * 32;
#pragma unroll
  for (int j = 0; j < 32; j += 8)
    tile[ty + j][tx] = src[(size_t)(y0 + ty + j) * DMODEL + x];
  __syncthreads();
  int xo = blockIdx.y * 32 + tx;
  int yo0 = blockIdx.x * 32;
#pragma unroll
  for (int j = 0; j < 32; j += 8)
    dst[(size_t)(yo0 + ty + j) * DMODEL + xo] = f2bf(tile[tx][ty + j]);
}

// ---------------- QKV GEMM: X[2048,1024] @ W -> q,k (head-major), vT (transposed) ----------------
__global__ __launch_bounds__(256) void qkv_gemm_kernel(const short* __restrict__ Xb,
                                                       const short* __restrict__ Wt,
                                                       short* __restrict__ q,
                                                       short* __restrict__ k,
                                                       short* __restrict__ vT) {
  int wave = threadIdx.x >> 6;
  int lane = threadIdx.x & 63;
  int lr = lane & 15;
  int quad = lane >> 4;
  int m0 = blockIdx.y * 64 + wave * 16;
  int n0 = blockIdx.x * 64;

  const short* Arow = Xb + (size_t)(m0 + lr) * DMODEL + quad * 8;
  const short* Brow = Wt + (size_t)(n0 + lr) * DMODEL + quad * 8;

  floatx4 acc[4] = {};
  for (int kb = 0; kb < DMODEL; kb += 32) {
    short8 a = *(const short8*)(Arow + kb);
#pragma unroll
    for (int f = 0; f < 4; ++f) {
      short8 b = *(const short8*)(Brow + (size_t)f * 16 * DMODEL + kb);
      acc[f] = __builtin_amdgcn_mfma_f32_16x16x32_bf16(a, b, acc[f], 0, 0, 0);
    }
  }

#pragma unroll
  for (int f = 0; f < 4; ++f) {
    int n = n0 + f * 16 + lr;
    int which = n >> 10;  // 0=q, 1=k, 2=v
    int nn = n & 1023;
    int h = nn >> 6, d = nn & 63;
#pragma unroll
    for (int r = 0; r < 4; ++r) {
      int row = m0 + quad * 4 + r;
      short hv = f2bf(acc[f][r]);
      if (which == 0)
        q[((size_t)h * SEQ + row) * HDIM + d] = hv;
      else if (which == 1)
        k[((size_t)h * SEQ + row) * HDIM + d] = hv;
      else
        vT[((size_t)h * HDIM + d) * SEQ + row] = hv;
    }
  }
}

// ---------------- Fused attention: scores + softmax + probs-write + PV ----------------
// Block = 1 head x 16 Q rows. 4 waves each own 512 score cols in registers.
#define CHUNK 256
#define PSTR (CHUNK + 8)  // bf16 row stride, padded to break bank conflicts

__global__ __launch_bounds__(256) void attn_fused_kernel(const short* __restrict__ q,
                                                         const short* __restrict__ k,
                                                         const short* __restrict__ vT,
                                                         float* __restrict__ probs,
                                                         float* __restrict__ ctx) {
  __shared__ short pbuf[4][16 * PSTR];   // wave-private P chunks (bf16)
  __shared__ float partial[4][16][64];   // per-wave PV partials
  __shared__ float wred[4][16];          // cross-wave softmax reduce

  int h = blockIdx.y;
  int m0 = blockIdx.x * 16;
  int wave = threadIdx.x >> 6, lane = threadIdx.x & 63;
  int lr = lane & 15, quad = lane >> 4;
  int nb = wave * 512;

  // Q fragment: A[m=lr][k=quad*8+j], two 32-k steps
  const short* Q = q + ((size_t)h * SEQ + m0 + lr) * HDIM + quad * 8;
  short8 qa0 = *(const short8*)(Q);
  short8 qa1 = *(const short8*)(Q + 32);

  const short* K = k + (size_t)h * SEQ * HDIM + quad * 8;

  // ---- scores: 16 x 512 per wave, held in 32 floatx4 accumulators ----
  floatx4 s[32];
#pragma unroll
  for (int f = 0; f < 32; ++f) {
    const short* Kr = K + (size_t)(nb + f * 16 + lr) * HDIM;
    short8 b0 = *(const short8*)(Kr);
    short8 b1 = *(const short8*)(Kr + 32);
    floatx4 t = {};
    t = __builtin_amdgcn_mfma_f32_16x16x32_bf16(qa0, b0, t, 0, 0, 0);
    s[f] = __builtin_amdgcn_mfma_f32_16x16x32_bf16(qa1, b1, t, 0, 0, 0);
  }

  // ---- row max (scale by 1/8 first) ----
  float mrow[4] = {-3.4e38f, -3.4e38f, -3.4e38f, -3.4e38f};
#pragma unroll
  for (int f = 0; f < 32; ++f)
#pragma unroll
    for (int r = 0; r < 4; ++r) {
      s[f][r] *= 0.125f;
      mrow[r] = fmaxf(mrow[r], s[f][r]);
    }
#pragma unroll
  for (int off = 8; off >= 1; off >>= 1)
#pragma unroll
    for (int r = 0; r < 4; ++r) mrow[r] = fmaxf(mrow[r], __shfl_xor(mrow[r], off));
  if (lr == 0)
#pragma unroll
    for (int r = 0; r < 4; ++r) wred[wave][quad * 4 + r] = mrow[r];
  __syncthreads();
#pragma unroll
  for (int r = 0; r < 4; ++r) {
    int row = quad * 4 + r;
    mrow[r] = fmaxf(fmaxf(wred[0][row], wred[1][row]), fmaxf(wred[2][row], wred[3][row]));
  }
  __syncthreads();  // wred reused for sums

  // ---- exp + row sum ----
  float srow[4] = {0.f, 0.f, 0.f, 0.f};
#pragma unroll
  for (int f = 0; f < 32; ++f)
#pragma unroll
    for (int r = 0; r < 4; ++r) {
      float e = __expf(s[f][r] - mrow[r]);
      s[f][r] = e;
      srow[r] += e;
    }
#pragma unroll
  for (int off = 8; off >= 1; off >>= 1)
#pragma unroll
    for (int r = 0; r < 4; ++r) srow[r] += __shfl_xor(srow[r], off);
  if (lr == 0)
#pragma unroll
    for (int r = 0; r < 4; ++r) wred[wave][quad * 4 + r] = srow[r];
  __syncthreads();
  float inv[4];
#pragma unroll
  for (int r = 0; r < 4; ++r) {
    int row = quad * 4 + r;
    inv[r] = 1.0f / (wred[0][row] + wred[1][row] + wred[2][row] + wred[3][row]);
  }

  // ---- per-chunk: write probs to global, stage bf16 P in LDS, PV MFMA ----
  float* Pg = probs + ((size_t)h * SEQ + m0 + quad * 4) * SEQ + nb + lr;
  short* pw = pbuf[wave];
  const short* Vbase = vT + (size_t)h * HDIM * SEQ;
  floatx4 cacc[4] = {};

#pragma unroll
  for (int c = 0; c < 2; ++c) {
#pragma unroll
    for (int fi = 0; fi < 16; ++fi) {
      int f = c * 16 + fi;
#pragma unroll
      for (int r = 0; r < 4; ++r) {
        float p = s[f][r] * inv[r];
        Pg[(size_t)r * SEQ + f * 16] = p;
        pw[(quad * 4 + r) * PSTR + fi * 16 + lr] = f2bf(p);
      }
    }
    __syncthreads();  // drain LDS writes (lgkmcnt(0) before barrier)
#pragma unroll
    for (int kt = 0; kt < CHUNK; kt += 32) {
      short8 a = *(const short8*)(pw + lr * PSTR + kt + quad * 8);
#pragma unroll
      for (int f = 0; f < 4; ++f) {
        short8 b = *(const short8*)(Vbase + (size_t)(f * 16 + lr) * SEQ + nb + c * CHUNK + kt + quad * 8);
        cacc[f] = __builtin_amdgcn_mfma_f32_16x16x32_bf16(a, b, cacc[f], 0, 0, 0);
      }
    }
    __syncthreads();  // protect pbuf WAR across chunk boundary
  }

  // ---- cross-wave ctx reduction ----
#pragma unroll
  for (int f = 0; f < 4; ++f)
#pragma unroll
    for (int r = 0; r < 4; ++r) partial[wave][quad * 4 + r][f * 16 + lr] = cacc[f][r];
  __syncthreads();
  for (int e = threadIdx.x; e < 16 * 64; e += 256) {
    int m = e >> 6, d = e & 63;
    float v = partial[0][m][d] + partial[1][m][d] + partial[2][m][d] + partial[3][m][d];
    ctx[(size_t)(m0 + m) * DMODEL + h * HDIM + d] = v;
  }
}

extern "C" void kernel_launch(void* const* d_in, const int* in_sizes, int n_in,
                              void* d_out, int out_size, void* d_ws, size_t ws_size,
                              hipStream_t stream) {
  const float* X = (const float*)d_in[0];
  const float* Wq = (const float*)d_in[1];
  const float* Wk = (const float*)d_in[2];
  const float* Wv = (const float*)d_in[3];

  float* ctx = (float*)d_out;
  float* probs = (float*)d_out + (size_t)SEQ * DMODEL;

  short* Xb = (short*)d_ws;                      // [2048][1024] bf16
  short* Wt = Xb + (size_t)SEQ * DMODEL;         // [3*1024][1024] bf16 (B^T)
  short* qb = Wt + (size_t)3 * DMODEL * DMODEL;  // [16][2048][64]
  short* kb = qb + (size_t)NHEADS * SEQ * HDIM;  // [16][2048][64]
  short* vT = kb + (size_t)NHEADS * SEQ * HDIM;  // [16][64][2048]

  cast_bf16_kernel<<<(SEQ * DMODEL + 255) / 256, 256, 0, stream>>>(X, Xb, SEQ * DMODEL);
  dim3 tb(32, 8), tg(32, 32);
  transpose_cast_kernel<<<tg, tb, 0, stream>>>(Wq, Wt);
  transpose_cast_kernel<<<tg, tb, 0, stream>>>(Wk, Wt + (size_t)DMODEL * DMODEL);
  transpose_cast_kernel<<<tg, tb, 0, stream>>>(Wv, Wt + (size_t)2 * DMODEL * DMODEL);

  qkv_gemm_kernel<<<dim3(48, 32), 256, 0, stream>>>(Xb, Wt, qb, kb, vT);
  attn_fused_kernel<<<dim3(SEQ / 16, NHEADS), 256, 0, stream>>>(qb, kb, vT, probs, ctx);
}